// Round 1
// baseline (9.764 us; speedup 1.0000x reference)
//
#include <hip/hip_runtime.h>
#include <hip/hip_bf16.h>

#define NF 64  // N_FACTORS

// One 64-lane wave per output element. Lane l loads factor l of both
// embedding rows (coalesced 256B row reads), dot via shfl reduction.
__global__ __launch_bounds__(256) void MF_1331439862348_kernel(
    const int* __restrict__ users, const int* __restrict__ items,
    const float* __restrict__ user_emb, const float* __restrict__ item_emb,
    const float* __restrict__ user_bias, const float* __restrict__ item_bias,
    const float* __restrict__ bias, float* __restrict__ out, int batch)
{
    const int wave = (int)((blockIdx.x * blockDim.x + threadIdx.x) >> 6);
    const int lane = threadIdx.x & 63;
    if (wave >= batch) return;

    const int u = users[wave];
    const int it = items[wave];

    const float ue = user_emb[(size_t)u * NF + lane];
    const float ie = item_emb[(size_t)it * NF + lane];
    float p = ue * ie;

    // 64-lane sum reduction
    #pragma unroll
    for (int off = 32; off > 0; off >>= 1)
        p += __shfl_down(p, off, 64);

    if (lane == 0) {
        float v = user_bias[u] + item_bias[it] + bias[0] + p;
        v = fminf(fmaxf(v, 1.0f), 5.0f);
        out[wave] = v;
    }
}

extern "C" void kernel_launch(void* const* d_in, const int* in_sizes, int n_in,
                              void* d_out, int out_size, void* d_ws, size_t ws_size,
                              hipStream_t stream) {
    const int*   users     = (const int*)  d_in[0];
    const int*   items     = (const int*)  d_in[1];
    const float* user_emb  = (const float*)d_in[2];
    const float* item_emb  = (const float*)d_in[3];
    const float* user_bias = (const float*)d_in[4];
    const float* item_bias = (const float*)d_in[5];
    const float* bias      = (const float*)d_in[6];
    float* out = (float*)d_out;

    const int batch = in_sizes[0];
    const int block = 256;                    // 4 waves/block
    const int waves_per_block = block / 64;
    const int grid = (batch + waves_per_block - 1) / waves_per_block;

    MF_1331439862348_kernel<<<grid, block, 0, stream>>>(
        users, items, user_emb, item_emb, user_bias, item_bias, bias, out, batch);
}

// Round 2
// 9.740 us; speedup vs baseline: 1.0024x; 1.0024x over previous
//
#include <hip/hip_runtime.h>
#include <hip/hip_bf16.h>

#define NF 64  // N_FACTORS

// 16 lanes per output element; each lane loads float4 from both embedding
// rows (16 lanes x 16B = 256B coalesced row read). 4 outputs per wave.
// Dot via 4-step shfl reduction within each 16-lane group.
__global__ __launch_bounds__(256) void MF_1331439862348_kernel(
    const int* __restrict__ users, const int* __restrict__ items,
    const float* __restrict__ user_emb, const float* __restrict__ item_emb,
    const float* __restrict__ user_bias, const float* __restrict__ item_bias,
    const float* __restrict__ bias, float* __restrict__ out, int batch)
{
    const int tid = blockIdx.x * blockDim.x + threadIdx.x;
    const int out_idx = tid >> 4;          // 16 lanes per output
    const int sub = threadIdx.x & 15;      // lane within 16-lane group
    if (out_idx >= batch) return;

    const int u  = users[out_idx];
    const int it = items[out_idx];

    const float4 ue = *(const float4*)&user_emb[(size_t)u * NF + sub * 4];
    const float4 ie = *(const float4*)&item_emb[(size_t)it * NF + sub * 4];
    float p = ue.x * ie.x + ue.y * ie.y + ue.z * ie.z + ue.w * ie.w;

    // 16-lane tree reduction (offsets stay within the group for the lanes
    // that feed sub==0; cross-group pulls only pollute unused lanes)
    #pragma unroll
    for (int off = 8; off > 0; off >>= 1)
        p += __shfl_down(p, off, 64);

    if (sub == 0) {
        float v = user_bias[u] + item_bias[it] + bias[0] + p;
        out[out_idx] = fminf(fmaxf(v, 1.0f), 5.0f);
    }
}

extern "C" void kernel_launch(void* const* d_in, const int* in_sizes, int n_in,
                              void* d_out, int out_size, void* d_ws, size_t ws_size,
                              hipStream_t stream) {
    const int*   users     = (const int*)  d_in[0];
    const int*   items     = (const int*)  d_in[1];
    const float* user_emb  = (const float*)d_in[2];
    const float* item_emb  = (const float*)d_in[3];
    const float* user_bias = (const float*)d_in[4];
    const float* item_bias = (const float*)d_in[5];
    const float* bias      = (const float*)d_in[6];
    float* out = (float*)d_out;

    const int batch = in_sizes[0];
    const int block = 256;                          // 16 outputs per block
    const int total_threads = batch * 16;
    const int grid = (total_threads + block - 1) / block;

    MF_1331439862348_kernel<<<grid, block, 0, stream>>>(
        users, items, user_emb, item_emb, user_bias, item_bias, bias, out, batch);
}